// Round 6
// baseline (1435.844 us; speedup 1.0000x reference)
//
#include <hip/hip_runtime.h>
#include <stdint.h>

// ---------------------------------------------------------------------------
// HGP-SL GNN forward on MI355X.  Round 6.
// KEY FACTS:
//  - All float inputs are FLOAT32 (setup_inputs).
//  - All three outputs are FLOAT32 (reference output dtype; the bf16 label in
//    the test is a hardcoded string). Round 4/5's 3.859375 absmax == packed
//    bf16 logp (-2.3) read as f32 against ref x_ (+1.6) -- dtype bug, now fixed.
// Workspace map (MB), peak ~118.1:
//  [0,64)    H ; after H dead: ADJ1 [0,32), X2 [32,64); then X3 [32,48), H3 [48,64)
//  [4,68)    XW (staggered +4MB over H; 16 seq. aggregate launches)
//  [68,72)   CSR      [72,73) degree arrays   [73,73.25) SCORE
//  [76,108)  H1 -> reused as H2
//  [108,116) ADJ2
//  [116,~118.1) persistent misc
// ---------------------------------------------------------------------------

#define B_   128
#define N_   512
#define NN_  65536
#define E_   1048576
#define LAMB_ 1.0f

__device__ inline float waveReduceSum(float v) {
    #pragma unroll
    for (int o = 32; o > 0; o >>= 1) v += __shfl_down(v, o, 64);
    return v;
}

// ---------------- 1. fp32 SIMT GEMM: XW = x @ W1  (65536x512 @ 512x256) -----
__global__ __launch_bounds__(256) void gemm_xw_kernel(
    const float* __restrict__ A, const float* __restrict__ Bm, float* __restrict__ C) {
    int m0 = blockIdx.x * 64, n0 = blockIdx.y * 64;
    __shared__ float As[16 * 68], Bs[16 * 68];
    int tid = threadIdx.x, tx = tid & 15, ty = tid >> 4;
    float acc[4][4] = {{0.f}};
    for (int k0 = 0; k0 < 512; k0 += 16) {
        __syncthreads();
        #pragma unroll
        for (int i = 0; i < 4; i++) {
            int idx = tid + i * 256;
            int kk = idx & 15, m = idx >> 4;
            As[kk * 68 + m] = A[(size_t)(m0 + m) * 512 + k0 + kk];
        }
        #pragma unroll
        for (int i = 0; i < 4; i++) {
            int idx = tid + i * 256;
            int n = idx & 63, kk = idx >> 6;
            Bs[kk * 68 + n] = Bm[(size_t)(k0 + kk) * 256 + n0 + n];
        }
        __syncthreads();
        #pragma unroll
        for (int kk = 0; kk < 16; kk++) {
            float4 a = *(const float4*)&As[kk * 68 + ty * 4];
            float4 bv = *(const float4*)&Bs[kk * 68 + tx * 4];
            float av[4] = {a.x, a.y, a.z, a.w};
            float bb[4] = {bv.x, bv.y, bv.z, bv.w};
            #pragma unroll
            for (int i2 = 0; i2 < 4; i2++)
                #pragma unroll
                for (int j2 = 0; j2 < 4; j2++) acc[i2][j2] += av[i2] * bb[j2];
        }
    }
    #pragma unroll
    for (int i = 0; i < 4; i++)
        #pragma unroll
        for (int j = 0; j < 4; j++)
            C[(size_t)(m0 + ty * 4 + i) * 256 + n0 + tx * 4 + j] = acc[i][j];
}

// ---------------- 2. CSR build ----------------------------------------------
__global__ void count_kernel(const int* __restrict__ dst, int* __restrict__ indeg) {
    int e = blockIdx.x * 256 + threadIdx.x;
    if (e < E_) atomicAdd(&indeg[dst[e] & 65535], 1);
}
__global__ void scan_kernel(const int* __restrict__ indeg, int* __restrict__ rowstart,
                            int* __restrict__ cursor) {
    __shared__ int part[1024];
    int t = threadIdx.x;
    int base = t * 64;
    int s = 0;
    for (int i = 0; i < 64; i++) s += indeg[base + i];
    part[t] = s;
    __syncthreads();
    for (int off = 1; off < 1024; off <<= 1) {
        int v = (t >= off) ? part[t - off] : 0;
        __syncthreads();
        part[t] += v;
        __syncthreads();
    }
    int run = (t == 0) ? 0 : part[t - 1];
    for (int i = 0; i < 64; i++) {
        rowstart[base + i] = run;
        cursor[base + i] = run;
        run += indeg[base + i];
    }
}
__global__ void scatter_csr_kernel(const int* __restrict__ src, const int* __restrict__ dst,
                                   int* __restrict__ cursor, int* __restrict__ csr) {
    int e = blockIdx.x * 256 + threadIdx.x;
    if (e < E_) {
        int pos = atomicAdd(&cursor[dst[e] & 65535], 1);
        csr[pos & (E_ - 1)] = src[e] & 65535;
    }
}
__global__ void dinv_kernel(const int* __restrict__ indeg, float* __restrict__ dinv) {
    int i = blockIdx.x * 256 + threadIdx.x;
    dinv[i] = rsqrtf((float)indeg[i] + 1.0f);
}

// ---------------- 3. sparse GCN aggregate (staggered sub-range) -------------
__global__ void aggregate_kernel(const float4* __restrict__ xw, const int* __restrict__ rowstart,
                                 const int* __restrict__ indeg, const float* __restrict__ dinv,
                                 const int* __restrict__ csr, const float* __restrict__ b1,
                                 float4* __restrict__ h, float4* __restrict__ xout,
                                 int node_base) {
    int node = node_base + blockIdx.x * 4 + (threadIdx.x >> 6);
    int lane = threadIdx.x & 63;
    int beg = rowstart[node], cnt = indeg[node];
    float di = dinv[node];
    float4 acc = make_float4(0.f, 0.f, 0.f, 0.f);
    for (int t = 0; t < cnt; t++) {
        int s = csr[(beg + t) & (E_ - 1)] & 65535;
        float w = dinv[s] * di;
        float4 v = xw[(size_t)s * 64 + lane];
        acc.x += v.x * w; acc.y += v.y * w; acc.z += v.z * w; acc.w += v.w * w;
    }
    {
        float w = di * di;
        float4 v = xw[(size_t)node * 64 + lane];
        acc.x += v.x * w; acc.y += v.y * w; acc.z += v.z * w; acc.w += v.w * w;
    }
    int c4 = lane * 4;
    acc.x = fmaxf(acc.x + b1[c4 + 0], 0.f);
    acc.y = fmaxf(acc.y + b1[c4 + 1], 0.f);
    acc.z = fmaxf(acc.z + b1[c4 + 2], 0.f);
    acc.w = fmaxf(acc.w + b1[c4 + 3], 0.f);
    h[(size_t)node * 64 + lane] = acc;
    xout[(size_t)node * 64 + lane] = acc;     // x__ output, f32
}

// ---------------- 4. pool_sparse score --------------------------------------
__global__ void score_kernel(const float4* __restrict__ h, const int* __restrict__ rowstart,
                             const int* __restrict__ indeg, const int* __restrict__ csr,
                             float* __restrict__ score) {
    int node = blockIdx.x * 4 + (threadIdx.x >> 6);
    int lane = threadIdx.x & 63;
    int beg = rowstart[node], cnt = indeg[node];
    float degp = fmaxf((float)cnt, 1.0f);
    float4 nb = make_float4(0.f, 0.f, 0.f, 0.f);
    for (int t = 0; t < cnt; t++) {
        int s = csr[(beg + t) & (E_ - 1)] & 65535;
        float4 v = h[(size_t)s * 64 + lane];
        nb.x += v.x; nb.y += v.y; nb.z += v.z; nb.w += v.w;
    }
    float4 x = h[(size_t)node * 64 + lane];
    float p = fabsf(x.x - nb.x / degp) + fabsf(x.y - nb.y / degp) +
              fabsf(x.z - nb.z / degp) + fabsf(x.w - nb.w / degp);
    p = waveReduceSum(p);
    if (lane == 0) score[node] = p;
}

// ---------------- 5. bitonic top-k (full sort, descending, tie->lower idx) --
__global__ void topk_kernel(const float* __restrict__ score, int n, int k,
                            int* __restrict__ out_local, int* __restrict__ rank, int Nfull) {
    int b = blockIdx.x, i = threadIdx.x;
    __shared__ float ss[512];
    __shared__ int si[512];
    ss[i] = score[b * n + i];
    si[i] = i;
    __syncthreads();
    for (int kk = 2; kk <= n; kk <<= 1)
        for (int j = kk >> 1; j > 0; j >>= 1) {
            int l = i ^ j;
            if (l > i) {
                float s1 = ss[i], s2 = ss[l];
                int i1 = si[i], i2 = si[l];
                bool up = ((i & kk) == 0);
                bool before = (s1 > s2) || (s1 == s2 && i1 < i2);
                bool doswap = up ? (!before) : before;
                if (doswap) { ss[i] = s2; ss[l] = s1; si[i] = i2; si[l] = i1; }
            }
            __syncthreads();
        }
    if (i < k) {
        int loc = si[i];
        out_local[b * k + i] = loc;
        if (rank) rank[b * Nfull + loc] = i;
    }
}

// ---------------- gathers / readouts / e-f dots -----------------------------
__global__ void gather_rows_kernel(const float4* __restrict__ src, const int* __restrict__ idxl,
                                   int k, int Nfull, float4* __restrict__ dstp) {
    int row = blockIdx.x;
    int b = row / k;
    int node = b * Nfull + (idxl[row] & (Nfull - 1));
    dstp[(size_t)row * 64 + threadIdx.x] = src[(size_t)node * 64 + threadIdx.x];
}
__global__ void readout_kernel(const float* __restrict__ x, int k, float* __restrict__ out) {
    int b = blockIdx.x, c = threadIdx.x;
    float mx = -1e30f, sm = 0.f;
    for (int j = 0; j < k; j++) {
        float v = x[((size_t)(b * k + j)) * 256 + c];
        mx = fmaxf(mx, v);
        sm += v;
    }
    out[b * 512 + c] = mx;
    out[b * 512 + 256 + c] = sm * (1.0f / (float)k);
}
__global__ void readout_idx_kernel(const float* __restrict__ x, const int* __restrict__ idx,
                                   int k, int Nfull, float* __restrict__ out) {
    int b = blockIdx.x, c = threadIdx.x;
    float mx = -1e30f, sm = 0.f;
    for (int j = 0; j < k; j++) {
        int node = b * Nfull + (idx[b * k + j] & (Nfull - 1));
        float v = x[(size_t)node * 256 + c];
        mx = fmaxf(mx, v);
        sm += v;
    }
    out[b * 512 + c] = mx;
    out[b * 512 + 256 + c] = sm * (1.0f / (float)k);
}
__global__ void ef_plain_kernel(const float4* __restrict__ x, const float* __restrict__ att,
                                float* __restrict__ e, float* __restrict__ f) {
    int row = blockIdx.x * 4 + (threadIdx.x >> 6);
    int lane = threadIdx.x & 63;
    float4 v = x[(size_t)row * 64 + lane];
    const float* ap = att + lane * 8;
    float es = v.x * ap[0] + v.y * ap[2] + v.z * ap[4] + v.w * ap[6];
    float fs = v.x * ap[1] + v.y * ap[3] + v.z * ap[5] + v.w * ap[7];
    es = waveReduceSum(es);
    fs = waveReduceSum(fs);
    if (lane == 0) { e[row] = es; f[row] = fs; }
}
__global__ void ef_idx_kernel(const float4* __restrict__ x, const int* __restrict__ idx,
                              int k, int Nfull, const float* __restrict__ att,
                              float* __restrict__ e, float* __restrict__ f) {
    int row = blockIdx.x * 4 + (threadIdx.x >> 6);
    int lane = threadIdx.x & 63;
    int b = row / k;
    int node = b * Nfull + (idx[row] & (Nfull - 1));
    float4 v = x[(size_t)node * 64 + lane];
    const float* ap = att + lane * 8;
    float es = v.x * ap[0] + v.y * ap[2] + v.z * ap[4] + v.w * ap[6];
    float fs = v.x * ap[1] + v.y * ap[3] + v.z * ap[5] + v.w * ap[7];
    es = waveReduceSum(es);
    fs = waveReduceSum(fs);
    if (lane == 0) { e[row] = es; f[row] = fs; }
}

// ---------------- A_ind scatter & softmax & rowsums -------------------------
__global__ void scatter_A_kernel(const int* __restrict__ src, const int* __restrict__ dst,
                                 const int* __restrict__ rank, float* __restrict__ adj1) {
    int e = blockIdx.x * 256 + threadIdx.x;
    if (e >= E_) return;
    int s = src[e] & 65535, d = dst[e] & 65535;
    int ns = rank[s], nd = rank[d];
    if ((unsigned)ns < 256u && (unsigned)nd < 256u) {
        int g = s >> 9;
        adj1[(size_t)g * 65536 + ns * 256 + nd] = 1.0f;
    }
}
__global__ void softmax_adj_kernel(float* __restrict__ adj, const float* __restrict__ e,
                                   const float* __restrict__ f, int k) {
    int row = blockIdx.x;
    int b = row / k;
    int c = threadIdx.x;
    __shared__ float red[256];
    float v = adj[(size_t)row * k + c];
    float lg = e[row] + f[b * k + c] + LAMB_ * v;
    red[c] = lg;
    __syncthreads();
    for (int s = k >> 1; s > 0; s >>= 1) {
        if (c < s) red[c] = fmaxf(red[c], red[c + s]);
        __syncthreads();
    }
    float mx = red[0];
    __syncthreads();
    float ex = expf(lg - mx);
    red[c] = ex;
    __syncthreads();
    for (int s = k >> 1; s > 0; s >>= 1) {
        if (c < s) red[c] += red[c + s];
        __syncthreads();
    }
    adj[(size_t)row * k + c] = ex / red[0];
}
__global__ void rowsum_kernel(const float* __restrict__ adj, int k,
                              float* __restrict__ rowsum, float* __restrict__ dinv) {
    int row = blockIdx.x * 4 + (threadIdx.x >> 6);
    int lane = threadIdx.x & 63;
    float s = 0.f;
    for (int c = lane; c < k; c += 64) s += adj[(size_t)row * k + c];
    s = waveReduceSum(s);
    if (lane == 0) { rowsum[row] = s; dinv[row] = rsqrtf(s + 1.0f); }
}
__global__ void gather_adj2_kernel(const float* __restrict__ adj1, const int* __restrict__ idx2,
                                   float* __restrict__ adj2) {
    int ii = blockIdx.x, b = blockIdx.y, jj = threadIdx.x;
    int ri = idx2[b * 128 + ii] & 255, rj = idx2[b * 128 + jj] & 255;
    adj2[((size_t)(b * 128 + ii)) * 128 + jj] = adj1[(size_t)b * 65536 + ri * 256 + rj];
}
__global__ void bn_kernel(const float* g, const float* be,
                          const float* me, const float* va,
                          float* sBN, float* tBN) {
    int c = threadIdx.x;
    float s = g[c] * rsqrtf(va[c] + 1e-5f);
    sBN[c] = s;
    tBN[c] = be[c] - me[c] * s;
}

// ---------------- SIMT fp32 tiled GEMMs (64x64 tile, BK=16) -----------------
#define GEMM_PROLOG \
    int b = blockIdx.z; \
    int m0 = blockIdx.x * 64, n0 = blockIdx.y * 64; \
    __shared__ float As[16 * 68], Bs[16 * 68]; \
    int tid = threadIdx.x, tx = tid & 15, ty = tid >> 4; \
    float acc[4][4] = {{0.f}}; \
    (void)b;

#define GEMM_INNER \
    __syncthreads(); \
    _Pragma("unroll") \
    for (int kk = 0; kk < 16; kk++) { \
        float4 a = *(const float4*)&As[kk * 68 + ty * 4]; \
        float4 bv = *(const float4*)&Bs[kk * 68 + tx * 4]; \
        float av[4] = {a.x, a.y, a.z, a.w}; \
        float bb[4] = {bv.x, bv.y, bv.z, bv.w}; \
        _Pragma("unroll") \
        for (int i2 = 0; i2 < 4; i2++) \
            _Pragma("unroll") \
            for (int j2 = 0; j2 < 4; j2++) acc[i2][j2] += av[i2] * bb[j2]; \
    }

// (a) X2 = dinv1_row * (BN(H1) @ W2)
__global__ __launch_bounds__(256) void gemm_x2_kernel(
    const float* __restrict__ H1, const float* __restrict__ W2,
    const float* __restrict__ sBN, const float* __restrict__ tBN,
    const float* __restrict__ dinv1, float* __restrict__ X2) {
    GEMM_PROLOG
    const float* A = H1 + (size_t)b * 65536;
    for (int k0 = 0; k0 < 256; k0 += 16) {
        __syncthreads();
        #pragma unroll
        for (int i = 0; i < 4; i++) {
            int idx = tid + i * 256;
            int kk = idx & 15, m = idx >> 4;
            As[kk * 68 + m] = A[(m0 + m) * 256 + k0 + kk] * sBN[k0 + kk] + tBN[k0 + kk];
        }
        #pragma unroll
        for (int i = 0; i < 4; i++) {
            int idx = tid + i * 256;
            int n = idx & 63, kk = idx >> 6;
            Bs[kk * 68 + n] = W2[(k0 + kk) * 256 + n0 + n];
        }
        GEMM_INNER
    }
    #pragma unroll
    for (int i = 0; i < 4; i++) {
        int row = m0 + ty * 4 + i;
        float dv = dinv1[b * 256 + row];
        #pragma unroll
        for (int j = 0; j < 4; j++)
            X2[(size_t)b * 65536 + row * 256 + n0 + tx * 4 + j] = acc[i][j] * dv;
    }
}

// (b) H2 = relu(dinv1_i*(ADJ1@X2 + X2_i) + b2)
__global__ __launch_bounds__(256) void gemm_h2_kernel(
    const float* __restrict__ ADJ1, const float* __restrict__ X2,
    const float* __restrict__ dinv1, const float* __restrict__ b2,
    float* __restrict__ H2) {
    GEMM_PROLOG
    const float* A = ADJ1 + (size_t)b * 65536;
    const float* Bp = X2 + (size_t)b * 65536;
    for (int k0 = 0; k0 < 256; k0 += 16) {
        __syncthreads();
        #pragma unroll
        for (int i = 0; i < 4; i++) {
            int idx = tid + i * 256;
            int kk = idx & 15, m = idx >> 4;
            As[kk * 68 + m] = A[(m0 + m) * 256 + k0 + kk];
        }
        #pragma unroll
        for (int i = 0; i < 4; i++) {
            int idx = tid + i * 256;
            int n = idx & 63, kk = idx >> 6;
            Bs[kk * 68 + n] = Bp[(k0 + kk) * 256 + n0 + n];
        }
        GEMM_INNER
    }
    #pragma unroll
    for (int i = 0; i < 4; i++) {
        int row = m0 + ty * 4 + i;
        float dv = dinv1[b * 256 + row];
        #pragma unroll
        for (int j = 0; j < 4; j++) {
            int col = n0 + tx * 4 + j;
            float v = (acc[i][j] + X2[(size_t)b * 65536 + row * 256 + col]) * dv + b2[col];
            H2[(size_t)b * 65536 + row * 256 + col] = fmaxf(v, 0.f);
        }
    }
}

// (c) score2 += sum_cols |H2 - (ADJ1@H2)/deg|
__global__ __launch_bounds__(256) void gemm_score_kernel(
    const float* __restrict__ ADJ1, const float* __restrict__ H2,
    const float* __restrict__ rowsum1, float* __restrict__ score2) {
    GEMM_PROLOG
    const float* A = ADJ1 + (size_t)b * 65536;
    const float* Bp = H2 + (size_t)b * 65536;
    for (int k0 = 0; k0 < 256; k0 += 16) {
        __syncthreads();
        #pragma unroll
        for (int i = 0; i < 4; i++) {
            int idx = tid + i * 256;
            int kk = idx & 15, m = idx >> 4;
            As[kk * 68 + m] = A[(m0 + m) * 256 + k0 + kk];
        }
        #pragma unroll
        for (int i = 0; i < 4; i++) {
            int idx = tid + i * 256;
            int n = idx & 63, kk = idx >> 6;
            Bs[kk * 68 + n] = Bp[(k0 + kk) * 256 + n0 + n];
        }
        GEMM_INNER
    }
    float rpart[4];
    #pragma unroll
    for (int i = 0; i < 4; i++) {
        int row = m0 + ty * 4 + i;
        float deg = fmaxf(rowsum1[b * 256 + row], 1e-9f);
        float s = 0.f;
        #pragma unroll
        for (int j = 0; j < 4; j++) {
            int col = n0 + tx * 4 + j;
            s += fabsf(H2[(size_t)b * 65536 + row * 256 + col] - acc[i][j] / deg);
        }
        rpart[i] = s;
    }
    __syncthreads();
    #pragma unroll
    for (int i = 0; i < 4; i++) As[(ty * 4 + i) * 17 + tx] = rpart[i];
    __syncthreads();
    if (tid < 64) {
        float s = 0.f;
        #pragma unroll
        for (int x = 0; x < 16; x++) s += As[tid * 17 + x];
        atomicAdd(&score2[b * 256 + m0 + tid], s);
    }
}

// (d) X3[sel] = dinv2_sel * (H2[idx2[sel]] @ W3)
__global__ __launch_bounds__(256) void gemm_x3_kernel(
    const float* __restrict__ H2, const int* __restrict__ idx2,
    const float* __restrict__ W3,
    const float* __restrict__ dinv2, float* __restrict__ X3) {
    GEMM_PROLOG
    __shared__ int rowsS[64];
    if (tid < 64) rowsS[tid] = b * 256 + (idx2[b * 128 + m0 + tid] & 255);
    for (int k0 = 0; k0 < 256; k0 += 16) {
        __syncthreads();
        #pragma unroll
        for (int i = 0; i < 4; i++) {
            int idx = tid + i * 256;
            int kk = idx & 15, m = idx >> 4;
            As[kk * 68 + m] = H2[(size_t)rowsS[m] * 256 + k0 + kk];
        }
        #pragma unroll
        for (int i = 0; i < 4; i++) {
            int idx = tid + i * 256;
            int n = idx & 63, kk = idx >> 6;
            Bs[kk * 68 + n] = W3[(k0 + kk) * 256 + n0 + n];
        }
        GEMM_INNER
    }
    #pragma unroll
    for (int i = 0; i < 4; i++) {
        int row = m0 + ty * 4 + i;
        float dv = dinv2[b * 128 + row];
        #pragma unroll
        for (int j = 0; j < 4; j++)
            X3[(size_t)b * 32768 + row * 256 + n0 + tx * 4 + j] = acc[i][j] * dv;
    }
}

// (e) H3 = relu(dinv2_i*(ADJ2@X3 + X3_i) + b3), K=128
__global__ __launch_bounds__(256) void gemm_h3_kernel(
    const float* __restrict__ ADJ2, const float* __restrict__ X3,
    const float* __restrict__ dinv2, const float* __restrict__ b3,
    float* __restrict__ H3) {
    GEMM_PROLOG
    const float* A = ADJ2 + (size_t)b * 16384;
    const float* Bp = X3 + (size_t)b * 32768;
    for (int k0 = 0; k0 < 128; k0 += 16) {
        __syncthreads();
        #pragma unroll
        for (int i = 0; i < 4; i++) {
            int idx = tid + i * 256;
            int kk = idx & 15, m = idx >> 4;
            As[kk * 68 + m] = A[(m0 + m) * 128 + k0 + kk];
        }
        #pragma unroll
        for (int i = 0; i < 4; i++) {
            int idx = tid + i * 256;
            int n = idx & 63, kk = idx >> 6;
            Bs[kk * 68 + n] = Bp[(k0 + kk) * 256 + n0 + n];
        }
        GEMM_INNER
    }
    #pragma unroll
    for (int i = 0; i < 4; i++) {
        int row = m0 + ty * 4 + i;
        float dv = dinv2[b * 128 + row];
        #pragma unroll
        for (int j = 0; j < 4; j++) {
            int col = n0 + tx * 4 + j;
            float v = (acc[i][j] + X3[(size_t)b * 32768 + row * 256 + col]) * dv + b3[col];
            H3[(size_t)b * 32768 + row * 256 + col] = fmaxf(v, 0.f);
        }
    }
}

// ---------------- head MLP (f32 outputs) ------------------------------------
__global__ void head_kernel(const float* __restrict__ x1, const float* __restrict__ x2,
                            const float* __restrict__ x3,
                            const float* __restrict__ w1, const float* __restrict__ b1,
                            const float* __restrict__ w2, const float* __restrict__ b2,
                            const float* __restrict__ w3, const float* __restrict__ b3,
                            float* __restrict__ out_x, float* __restrict__ out_lp) {
    int b = blockIdx.x, t = threadIdx.x;
    __shared__ float g[512], g1[256], g2[128], lg[10];
    __shared__ float lse;
    for (int i = t; i < 512; i += 256)
        g[i] = fmaxf(x1[b * 512 + i], 0.f) + fmaxf(x2[b * 512 + i], 0.f) + fmaxf(x3[b * 512 + i], 0.f);
    __syncthreads();
    {
        float acc = b1[t];
        for (int kk = 0; kk < 512; kk++) acc += g[kk] * w1[kk * 256 + t];
        g1[t] = fmaxf(acc, 0.f);
    }
    __syncthreads();
    if (t < 128) {
        float acc = b2[t];
        for (int kk = 0; kk < 256; kk++) acc += g1[kk] * w2[kk * 128 + t];
        float r = fmaxf(acc, 0.f);
        g2[t] = r;
        out_x[b * 128 + t] = r;
    }
    __syncthreads();
    if (t < 10) {
        float acc = b3[t];
        for (int kk = 0; kk < 128; kk++) acc += g2[kk] * w3[kk * 10 + t];
        lg[t] = acc;
    }
    __syncthreads();
    if (t == 0) {
        float m = -1e30f;
        for (int i = 0; i < 10; i++) m = fmaxf(m, lg[i]);
        float s = 0.f;
        for (int i = 0; i < 10; i++) s += expf(lg[i] - m);
        lse = m + logf(s);
    }
    __syncthreads();
    if (t < 10) out_lp[b * 10 + t] = lg[t] - lse;
}

// ---------------------------------------------------------------------------
extern "C" void kernel_launch(void* const* d_in, const int* in_sizes, int n_in,
                              void* d_out, int out_size, void* d_ws, size_t ws_size,
                              hipStream_t stream) {
    const float* X    = (const float*)d_in[0];
    const int*   EI   = (const int*)d_in[1];
    const float* W1   = (const float*)d_in[3];
    const float* B1v  = (const float*)d_in[4];
    const float* W2   = (const float*)d_in[5];
    const float* B2v  = (const float*)d_in[6];
    const float* W3   = (const float*)d_in[7];
    const float* B3v  = (const float*)d_in[8];
    const float* ATT1 = (const float*)d_in[9];
    const float* ATT2 = (const float*)d_in[10];
    const float* GAM  = (const float*)d_in[11];
    const float* BET  = (const float*)d_in[12];
    const float* MEA  = (const float*)d_in[13];
    const float* VAR  = (const float*)d_in[14];
    const float* L1W  = (const float*)d_in[15];
    const float* L1B  = (const float*)d_in[16];
    const float* L2W  = (const float*)d_in[17];
    const float* L2B  = (const float*)d_in[18];
    const float* L3W  = (const float*)d_in[19];
    const float* L3B  = (const float*)d_in[20];
    float* OUT = (float*)d_out;                 // f32 outputs!
    const int OFF_LOGP = 16384, OFF_XU = 17664;

    const int* src = EI;
    const int* dst = EI + E_;

    uint8_t* w = (uint8_t*)d_ws;
    const size_t MB = 1u << 20;
    float* Hp   = (float*)(w + 0);            // [0,64)
    float* XWp  = (float*)(w + 4 * MB);       // [4,68) staggered over Hp
    float* ADJ1 = (float*)(w + 0);            // [0,32)  after Hp dead
    float* X2   = (float*)(w + 32 * MB);      // [32,64) after Hp dead
    float* X3   = (float*)(w + 32 * MB);      // [32,48) after X2 dead
    float* H3   = (float*)(w + 48 * MB);      // [48,64)
    int*   CSR    = (int*)(w + 68 * MB);      // [68,72)
    int*   INDEG  = (int*)(w + 72 * MB);
    int*   RSTART = INDEG + 65536;
    int*   CURSOR = RSTART + 65536;
    float* DINV   = (float*)(CURSOR + 65536);
    float* SCORE  = (float*)(w + 73 * MB);
    float* H1   = (float*)(w + 76 * MB);      // [76,108) -> reused as H2
    float* H2   = H1;
    float* ADJ2 = (float*)(w + 108 * MB);     // [108,116)
    uint8_t* mp = w + 116 * MB;               // persistent misc
    int*   RANK   = (int*)mp;   mp += 256 * 1024;
    int*   IDX1   = (int*)mp;   mp += 128 * 1024;
    int*   IDX2   = (int*)mp;   mp += 64 * 1024;
    float* E1     = (float*)mp; mp += 128 * 1024;
    float* F1     = (float*)mp; mp += 128 * 1024;
    float* E2     = (float*)mp; mp += 64 * 1024;
    float* F2     = (float*)mp; mp += 64 * 1024;
    float* RS1    = (float*)mp; mp += 128 * 1024;
    float* DV1    = (float*)mp; mp += 128 * 1024;
    float* RS2    = (float*)mp; mp += 64 * 1024;
    float* DV2    = (float*)mp; mp += 64 * 1024;
    float* SC2    = (float*)mp; mp += 128 * 1024;
    float* SBN    = (float*)mp; mp += 4 * 1024;
    float* TBN    = (float*)mp; mp += 4 * 1024;
    float* X1R    = (float*)mp; mp += 256 * 1024;
    float* X2R    = (float*)mp; mp += 256 * 1024;
    float* X3R    = (float*)mp; mp += 256 * 1024;

    hipMemsetAsync(INDEG, 0, 256 * 1024, stream);
    hipMemsetAsync(RANK, 0xFF, 256 * 1024, stream);
    hipMemsetAsync(SC2, 0, 128 * 1024, stream);

    gemm_xw_kernel<<<dim3(1024, 4), 256, 0, stream>>>(X, W1, XWp);
    count_kernel<<<4096, 256, 0, stream>>>(dst, INDEG);
    scan_kernel<<<1, 1024, 0, stream>>>(INDEG, RSTART, CURSOR);
    scatter_csr_kernel<<<4096, 256, 0, stream>>>(src, dst, CURSOR, CSR);
    dinv_kernel<<<256, 256, 0, stream>>>(INDEG, DINV);
    for (int k = 0; k < 16; k++)
        aggregate_kernel<<<1024, 256, 0, stream>>>((const float4*)XWp, RSTART, INDEG, DINV,
                                                   CSR, B1v, (float4*)Hp,
                                                   (float4*)(OUT + OFF_XU), k * 4096);
    score_kernel<<<16384, 256, 0, stream>>>((const float4*)Hp, RSTART, INDEG, CSR, SCORE);
    topk_kernel<<<128, 512, 0, stream>>>(SCORE, 512, 256, IDX1, RANK, 512);
    gather_rows_kernel<<<32768, 64, 0, stream>>>((const float4*)Hp, IDX1, 256, 512, (float4*)H1);
    readout_kernel<<<128, 256, 0, stream>>>(H1, 256, X1R);
    ef_plain_kernel<<<8192, 256, 0, stream>>>((const float4*)H1, ATT1, E1, F1);
    hipMemsetAsync(ADJ1, 0, (size_t)32 * MB, stream);
    scatter_A_kernel<<<4096, 256, 0, stream>>>(src, dst, RANK, ADJ1);
    softmax_adj_kernel<<<32768, 256, 0, stream>>>(ADJ1, E1, F1, 256);
    rowsum_kernel<<<8192, 256, 0, stream>>>(ADJ1, 256, RS1, DV1);
    bn_kernel<<<1, 256, 0, stream>>>(GAM, BET, MEA, VAR, SBN, TBN);
    gemm_x2_kernel<<<dim3(4, 4, 128), 256, 0, stream>>>(H1, W2, SBN, TBN, DV1, X2);
    gemm_h2_kernel<<<dim3(4, 4, 128), 256, 0, stream>>>(ADJ1, X2, DV1, B2v, H2);
    gemm_score_kernel<<<dim3(4, 4, 128), 256, 0, stream>>>(ADJ1, H2, RS1, SC2);
    topk_kernel<<<128, 256, 0, stream>>>(SC2, 256, 128, IDX2, nullptr, 0);
    readout_idx_kernel<<<128, 256, 0, stream>>>(H2, IDX2, 128, 256, X2R);
    ef_idx_kernel<<<4096, 256, 0, stream>>>((const float4*)H2, IDX2, 128, 256, ATT2, E2, F2);
    gather_adj2_kernel<<<dim3(128, 128), 128, 0, stream>>>(ADJ1, IDX2, ADJ2);
    softmax_adj_kernel<<<16384, 128, 0, stream>>>(ADJ2, E2, F2, 128);
    rowsum_kernel<<<4096, 256, 0, stream>>>(ADJ2, 128, RS2, DV2);
    gemm_x3_kernel<<<dim3(2, 4, 128), 256, 0, stream>>>(H2, IDX2, W3, DV2, X3);
    gemm_h3_kernel<<<dim3(2, 4, 128), 256, 0, stream>>>(ADJ2, X3, DV2, B3v, H3);
    readout_kernel<<<128, 256, 0, stream>>>(H3, 128, X3R);
    head_kernel<<<128, 256, 0, stream>>>(X1R, X2R, X3R, L1W, L1B, L2W, L2B, L3W, L3B,
                                         OUT, OUT + OFF_LOGP);
}